// Round 5
// baseline (220.431 us; speedup 1.0000x reference)
//
#include <hip/hip_runtime.h>
#include <math.h>

#define HW 9216   // 96*96

typedef __attribute__((ext_vector_type(8))) short bf16x8;
typedef __attribute__((ext_vector_type(4))) float f32x4;
typedef unsigned short ushort_t;
typedef unsigned int uint_t;

__device__ __forceinline__ ushort_t f2bf(float f) {
    union { float f; uint_t u; } v; v.f = f;
    uint_t u = v.u + 0x7FFF + ((v.u >> 16) & 1);   // RNE
    return (ushort_t)(u >> 16);
}

// raw barrier: LDS-visibility only, no vmcnt drain (prefetches stay in flight)
#define BAR() do { asm volatile("s_waitcnt lgkmcnt(0)" ::: "memory"); \
                   __builtin_amdgcn_s_barrier(); } while (0)

// ------------------------------------------------------------------
// k1: 1x1 conv -> Gbt[p][o] bf16 (p = w*96+h permuted, o contiguous)
//     + xtile[jt][c][32] bf16 (fused: block jt covers exactly tile jt)
// ------------------------------------------------------------------
__global__ __launch_bounds__(256) void k1_conv(
        const float* __restrict__ x, const float* __restrict__ wc,
        const float* __restrict__ bc, ushort_t* __restrict__ Gbt,
        ushort_t* __restrict__ xtile) {
    __shared__ float wt[256][32];          // [c][o] 32KB
    __shared__ float red[8][32][33];       // [cg][px][o] padded
    int t = threadIdx.x;
    int jt = blockIdx.x;
    for (int i = t; i < 256 * 32; i += 256) {
        int o = i >> 8, c = i & 255;       // wc is [o][c]
        wt[c][o] = wc[i];
    }
    __syncthreads();
    int px = t & 31, cg = t >> 5;
    int n = jt * 32 + px;
    float acc[32];
    #pragma unroll
    for (int o = 0; o < 32; ++o) acc[o] = 0.f;
    int c0 = cg * 32;
    ushort_t* xt_out = &xtile[(size_t)jt * 8192 + px];
    for (int cc = 0; cc < 32; ++cc) {
        int c = c0 + cc;
        float xv = x[c * HW + n];
        xt_out[c * 32] = f2bf(xv);         // fused xtile emission
        #pragma unroll
        for (int o4 = 0; o4 < 8; ++o4) {
            float4 wv = *(const float4*)&wt[c][o4 * 4];
            acc[o4*4+0] = fmaf(wv.x, xv, acc[o4*4+0]);
            acc[o4*4+1] = fmaf(wv.y, xv, acc[o4*4+1]);
            acc[o4*4+2] = fmaf(wv.z, xv, acc[o4*4+2]);
            acc[o4*4+3] = fmaf(wv.w, xv, acc[o4*4+3]);
        }
    }
    #pragma unroll
    for (int o = 0; o < 32; ++o) red[cg][px][o] = acc[o];
    __syncthreads();
    int px2 = t >> 3, o2 = (t & 7) * 4;
    float s[4] = {0.f, 0.f, 0.f, 0.f};
    #pragma unroll
    for (int g = 0; g < 8; ++g) {
        s[0] += red[g][px2][o2 + 0];
        s[1] += red[g][px2][o2 + 1];
        s[2] += red[g][px2][o2 + 2];
        s[3] += red[g][px2][o2 + 3];
    }
    int n2 = jt * 32 + px2;
    int h = n2 / 96, w = n2 % 96;
    int p = w * 96 + h;
    uint2 pk;
    pk.x = (uint_t)f2bf(s[0] + bc[o2+0]) | ((uint_t)f2bf(s[1] + bc[o2+1]) << 16);
    pk.y = (uint_t)f2bf(s[2] + bc[o2+2]) | ((uint_t)f2bf(s[3] + bc[o2+3]) << 16);
    *(uint2*)&Gbt[p * 32 + o2] = pk;
}

// ------------------------------------------------------------------
// k2: per-row online softmax stats of S = G^T G via bf16 MFMA.
// ------------------------------------------------------------------
__global__ __launch_bounds__(512) void k2_stats(
        const ushort_t* __restrict__ Gbt, float* __restrict__ m_part,
        float* __restrict__ l_part) {
    __shared__ float mred[2][64], lred[2][64];
    int t = threadIdx.x;
    int w = t >> 6, l = t & 63;
    int l15 = l & 15, lg = l >> 4;
    int jb = blockIdx.x % 144, qs = blockIdx.x / 144;
    int j0 = jb * 64;
    int rf = w & 3, qp = w >> 2;
    bf16x8 aj = *(const bf16x8*)&Gbt[(j0 + rf * 16 + l15) * 32 + lg * 8];
    float m[4], lsum[4];
    #pragma unroll
    for (int r = 0; r < 4; ++r) { m[r] = -INFINITY; lsum[r] = 0.f; }
    int qbeg = qs * 1152;
    for (int tq = 0; tq < 18; ++tq) {
        int q0 = qbeg + tq * 64;
        bf16x8 b0 = *(const bf16x8*)&Gbt[(q0 + qp * 32 + l15) * 32 + lg * 8];
        bf16x8 b1 = *(const bf16x8*)&Gbt[(q0 + qp * 32 + 16 + l15) * 32 + lg * 8];
        f32x4 s0 = {0.f,0.f,0.f,0.f}, s1 = {0.f,0.f,0.f,0.f};
        s0 = __builtin_amdgcn_mfma_f32_16x16x32_bf16(aj, b0, s0, 0, 0, 0);
        s1 = __builtin_amdgcn_mfma_f32_16x16x32_bf16(aj, b1, s1, 0, 0, 0);
        #pragma unroll
        for (int r = 0; r < 4; ++r) {
            float tm = fmaxf(s0[r], s1[r]);
            float nm = fmaxf(m[r], tm);
            lsum[r] = lsum[r] * __expf(m[r] - nm)
                    + __expf(s0[r] - nm) + __expf(s1[r] - nm);
            m[r] = nm;
        }
    }
    #pragma unroll
    for (int off = 1; off < 16; off <<= 1) {
        #pragma unroll
        for (int r = 0; r < 4; ++r) {
            float mo = __shfl_xor(m[r], off);
            float lo = __shfl_xor(lsum[r], off);
            float nm = fmaxf(m[r], mo);
            lsum[r] = lsum[r] * __expf(m[r] - nm) + lo * __expf(mo - nm);
            m[r] = nm;
        }
    }
    if (l15 == 0) {
        #pragma unroll
        for (int r = 0; r < 4; ++r) {
            mred[qp][rf * 16 + lg * 4 + r] = m[r];
            lred[qp][rf * 16 + lg * 4 + r] = lsum[r];
        }
    }
    __syncthreads();
    if (t < 64) {
        float m0 = mred[0][t], m1 = mred[1][t];
        float l0 = lred[0][t], l1 = lred[1][t];
        float nm = fmaxf(m0, m1);
        float lv = l0 * __expf(m0 - nm) + l1 * __expf(m1 - nm);
        m_part[qs * HW + j0 + t] = nm;
        l_part[qs * HW + j0 + t] = lv;
    }
}

__global__ __launch_bounds__(256) void k2b_merge(
        const float* __restrict__ m_part, const float* __restrict__ l_part,
        float* __restrict__ mg, float* __restrict__ rlg) {
    int j = blockIdx.x * 256 + threadIdx.x;
    float nm = -INFINITY;
    #pragma unroll
    for (int s = 0; s < 8; ++s) nm = fmaxf(nm, m_part[s * HW + j]);
    float lv = 0.f;
    #pragma unroll
    for (int s = 0; s < 8; ++s)
        lv += l_part[s * HW + j] * __expf(m_part[s * HW + j] - nm);
    mg[j] = nm;
    rlg[j] = 1.0f / lv;
}

__global__ __launch_bounds__(256) void kzero(float* __restrict__ Z) {
    int i = blockIdx.x * 256 + threadIdx.x;
    *(float4*)&Z[i * 4] = make_float4(0.f, 0.f, 0.f, 0.f);
}

// phase A helper: 2 S-quadrant MFMAs + exp + packed write into Pbt[nbuf]
__device__ __forceinline__ void phaseA(
        bf16x8 ap0, bf16x8 ap1, bf16x8 bqA, int p0, ushort_t* pb,
        int w, int l15, int lg,
        const float* __restrict__ mg, const float* __restrict__ rlg) {
    f32x4 s0 = {0.f,0.f,0.f,0.f}, s1 = {0.f,0.f,0.f,0.f};
    s0 = __builtin_amdgcn_mfma_f32_16x16x32_bf16(ap0, bqA, s0, 0, 0, 0);
    s1 = __builtin_amdgcn_mfma_f32_16x16x32_bf16(ap1, bqA, s1, 0, 0, 0);
    int pr0 = p0 + lg * 4;
    int pr1 = p0 + 16 + lg * 4;
    float4 m0 = *(const float4*)&mg[pr0], r0 = *(const float4*)&rlg[pr0];
    float4 m1 = *(const float4*)&mg[pr1], r1 = *(const float4*)&rlg[pr1];
    uint2 pk0, pk1;
    pk0.x = (uint_t)f2bf(__expf(s0[0] - m0.x) * r0.x)
          | ((uint_t)f2bf(__expf(s0[1] - m0.y) * r0.y) << 16);
    pk0.y = (uint_t)f2bf(__expf(s0[2] - m0.z) * r0.z)
          | ((uint_t)f2bf(__expf(s0[3] - m0.w) * r0.w) << 16);
    pk1.x = (uint_t)f2bf(__expf(s1[0] - m1.x) * r1.x)
          | ((uint_t)f2bf(__expf(s1[1] - m1.y) * r1.y) << 16);
    pk1.y = (uint_t)f2bf(__expf(s1[2] - m1.z) * r1.z)
          | ((uint_t)f2bf(__expf(s1[3] - m1.w) * r1.w) << 16);
    ushort_t* row = pb + (w * 16 + l15) * 40;
    *(uint2*)&row[lg * 4]      = pk0;
    *(uint2*)&row[16 + lg * 4] = pk1;
}

// ------------------------------------------------------------------
// k3: Z[c,q] += sum_p xtile[c,p] * exp(S[p,q]-m_p)/l_p, bf16 MFMA.
// Grid = 72 q-blocks(128) x 8 p-splits = 576 x 512 (8 waves).
// Per 32-p tile: b-reads(buf) ; phase A(pt+1) -> buf^1 (pipelined);
// 16 PV MFMA ; one raw barrier. A-frags direct from tiled global.
// ------------------------------------------------------------------
__global__ __launch_bounds__(512, 4) void k3_pv(
        const ushort_t* __restrict__ xtile, const ushort_t* __restrict__ Gbt,
        const float* __restrict__ mg, const float* __restrict__ rlg,
        float* __restrict__ Z) {
    __shared__ ushort_t Pbt[2][128][40];   // [q][p], 80B rows
    int t = threadIdx.x;
    int w = t >> 6, l = t & 63;
    int l15 = l & 15, lg = l >> 4;
    int qb = blockIdx.x % 72, ps = blockIdx.x / 72;
    int q0 = qb * 128;
    int cg = w & 3, qh = w >> 2;           // phase-B wave tile: 64c x 64q
    // phase-A B-fragment: wave w owns q-quadrant w (loop-invariant)
    bf16x8 bqA = *(const bf16x8*)&Gbt[(q0 + w * 16 + l15) * 32 + lg * 8];
    f32x4 acc[4][4];
    #pragma unroll
    for (int ai = 0; ai < 4; ++ai)
        #pragma unroll
        for (int bi = 0; bi < 4; ++bi) acc[ai][bi] = (f32x4){0.f,0.f,0.f,0.f};
    int tile0 = ps * 36;
    int p0beg = ps * 1152;
    // prologue: compute A(0) into buf 0
    {
        bf16x8 ap0 = *(const bf16x8*)&Gbt[(p0beg + l15) * 32 + lg * 8];
        bf16x8 ap1 = *(const bf16x8*)&Gbt[(p0beg + 16 + l15) * 32 + lg * 8];
        phaseA(ap0, ap1, bqA, p0beg, &Pbt[0][0][0], w, l15, lg, mg, rlg);
    }
    // prefetch phase-A fragments for tile 1
    bf16x8 ap0_c = *(const bf16x8*)&Gbt[(p0beg + 32 + l15) * 32 + lg * 8];
    bf16x8 ap1_c = *(const bf16x8*)&Gbt[(p0beg + 48 + l15) * 32 + lg * 8];
    BAR();

    for (int pt = 0; pt < 36; ++pt) {
        int buf = pt & 1;
        // PV A-operands: dense rows from tiled global (L2-hot)
        const ushort_t* xt =
            &xtile[((size_t)(tile0 + pt) * 256 + cg * 64 + l15) * 32 + lg * 8];
        bf16x8 a0 = *(const bf16x8*)&xt[0];
        bf16x8 a1 = *(const bf16x8*)&xt[16 * 32];
        bf16x8 a2 = *(const bf16x8*)&xt[32 * 32];
        bf16x8 a3 = *(const bf16x8*)&xt[48 * 32];
        if (pt < 35) {   // pipelined phase A for tile pt+1 -> buf^1
            int p0n = p0beg + (pt + 1) * 32;
            phaseA(ap0_c, ap1_c, bqA, p0n, &Pbt[buf ^ 1][0][0],
                   w, l15, lg, mg, rlg);
            int p0nn = p0beg + ((pt < 34) ? (pt + 2) : 35) * 32;
            ap0_c = *(const bf16x8*)&Gbt[(p0nn + l15) * 32 + lg * 8];
            ap1_c = *(const bf16x8*)&Gbt[(p0nn + 16 + l15) * 32 + lg * 8];
        }
        // B-fragments from LDS (this tile)
        bf16x8 b0 = *(const bf16x8*)&Pbt[buf][qh * 64 + l15][lg * 8];
        bf16x8 b1 = *(const bf16x8*)&Pbt[buf][qh * 64 + 16 + l15][lg * 8];
        bf16x8 b2 = *(const bf16x8*)&Pbt[buf][qh * 64 + 32 + l15][lg * 8];
        bf16x8 b3 = *(const bf16x8*)&Pbt[buf][qh * 64 + 48 + l15][lg * 8];
        acc[0][0] = __builtin_amdgcn_mfma_f32_16x16x32_bf16(a0, b0, acc[0][0], 0,0,0);
        acc[0][1] = __builtin_amdgcn_mfma_f32_16x16x32_bf16(a0, b1, acc[0][1], 0,0,0);
        acc[0][2] = __builtin_amdgcn_mfma_f32_16x16x32_bf16(a0, b2, acc[0][2], 0,0,0);
        acc[0][3] = __builtin_amdgcn_mfma_f32_16x16x32_bf16(a0, b3, acc[0][3], 0,0,0);
        acc[1][0] = __builtin_amdgcn_mfma_f32_16x16x32_bf16(a1, b0, acc[1][0], 0,0,0);
        acc[1][1] = __builtin_amdgcn_mfma_f32_16x16x32_bf16(a1, b1, acc[1][1], 0,0,0);
        acc[1][2] = __builtin_amdgcn_mfma_f32_16x16x32_bf16(a1, b2, acc[1][2], 0,0,0);
        acc[1][3] = __builtin_amdgcn_mfma_f32_16x16x32_bf16(a1, b3, acc[1][3], 0,0,0);
        acc[2][0] = __builtin_amdgcn_mfma_f32_16x16x32_bf16(a2, b0, acc[2][0], 0,0,0);
        acc[2][1] = __builtin_amdgcn_mfma_f32_16x16x32_bf16(a2, b1, acc[2][1], 0,0,0);
        acc[2][2] = __builtin_amdgcn_mfma_f32_16x16x32_bf16(a2, b2, acc[2][2], 0,0,0);
        acc[2][3] = __builtin_amdgcn_mfma_f32_16x16x32_bf16(a2, b3, acc[2][3], 0,0,0);
        acc[3][0] = __builtin_amdgcn_mfma_f32_16x16x32_bf16(a3, b0, acc[3][0], 0,0,0);
        acc[3][1] = __builtin_amdgcn_mfma_f32_16x16x32_bf16(a3, b1, acc[3][1], 0,0,0);
        acc[3][2] = __builtin_amdgcn_mfma_f32_16x16x32_bf16(a3, b2, acc[3][2], 0,0,0);
        acc[3][3] = __builtin_amdgcn_mfma_f32_16x16x32_bf16(a3, b3, acc[3][3], 0,0,0);
        BAR();
    }
    int qcol = q0 + qh * 64 + l15;
    #pragma unroll
    for (int ai = 0; ai < 4; ++ai) {
        int crow = cg * 64 + ai * 16 + lg * 4;
        #pragma unroll
        for (int r = 0; r < 4; ++r) {
            float* zr = &Z[(size_t)(crow + r) * HW + qcol];
            #pragma unroll
            for (int bi = 0; bi < 4; ++bi)
                atomicAdd(zr + bi * 16, acc[ai][bi][r]);
        }
    }
}

// ------------------------------------------------------------------
// k4: per-c row softmax of Z (9216) fused with final softmax over W.
// 512 threads (8 waves) per row.
// ------------------------------------------------------------------
__global__ __launch_bounds__(512) void k4_softmax(
        const float* __restrict__ x, float* __restrict__ ZO) {
    __shared__ float zrow[HW];
    __shared__ float red[8];
    int t = threadIdx.x, c = blockIdx.x;
    int lane = t & 63, wid = t >> 6;
    const float* Zr = &ZO[(size_t)c * HW];
    float lm = -INFINITY;
    #pragma unroll
    for (int k = 0; k < 18; ++k) {
        float v = Zr[t + 512 * k];
        zrow[t + 512 * k] = v;
        lm = fmaxf(lm, v);
    }
    #pragma unroll
    for (int off = 32; off; off >>= 1) lm = fmaxf(lm, __shfl_xor(lm, off));
    if (lane == 0) red[wid] = lm;
    __syncthreads();
    float M = fmaxf(fmaxf(fmaxf(red[0], red[1]), fmaxf(red[2], red[3])),
                    fmaxf(fmaxf(red[4], red[5]), fmaxf(red[6], red[7])));
    __syncthreads();
    float ls = 0.f;
    #pragma unroll
    for (int k = 0; k < 18; ++k) {
        int i = t + 512 * k;
        float e = __expf(zrow[i] - M);
        zrow[i] = e;
        ls += e;
    }
    #pragma unroll
    for (int off = 32; off; off >>= 1) ls += __shfl_xor(ls, off);
    if (lane == 0) red[wid] = ls;
    __syncthreads();
    float rS = 1.0f / (red[0] + red[1] + red[2] + red[3]
                     + red[4] + red[5] + red[6] + red[7]);
    const float* xr = &x[(size_t)c * HW];
    float* outr = &ZO[(size_t)c * HW];
    for (int kk = 0; kk < 12; ++kk) {
        int h = wid + kk * 8;
        int base = h * 96;
        float v0 = fmaf(zrow[base + lane], rS, xr[base + lane]);
        float v1 = (lane < 32)
                 ? fmaf(zrow[base + 64 + lane], rS, xr[base + 64 + lane])
                 : -INFINITY;
        float mm = fmaxf(v0, v1);
        #pragma unroll
        for (int off = 32; off; off >>= 1) mm = fmaxf(mm, __shfl_xor(mm, off));
        float e0 = __expf(v0 - mm);
        float e1 = (lane < 32) ? __expf(v1 - mm) : 0.f;
        float ss = e0 + e1;
        #pragma unroll
        for (int off = 32; off; off >>= 1) ss += __shfl_xor(ss, off);
        float r = 1.0f / ss;
        outr[base + lane] = e0 * r;
        if (lane < 32) outr[base + 64 + lane] = e1 * r;
    }
}

extern "C" void kernel_launch(void* const* d_in, const int* in_sizes, int n_in,
                              void* d_out, int out_size, void* d_ws, size_t ws_size,
                              hipStream_t stream) {
    const float* x  = (const float*)d_in[0];   // [256,96,96]
    const float* wc = (const float*)d_in[1];   // [32,256]
    const float* bc = (const float*)d_in[2];   // [32]
    float* Z = (float*)d_out;                  // accum Z, then final out

    float* m_part = (float*)d_ws;              // 8*9216
    float* l_part = m_part + 8 * HW;           // 8*9216
    float* mg     = l_part + 8 * HW;           // 9216
    float* rlg    = mg + HW;                   // 9216
    ushort_t* xtile = (ushort_t*)(rlg + HW);   // 288*256*32 bf16 (tiled x)
    ushort_t* Gbt   = xtile + 256 * HW;        // 9216*32 bf16

    k1_conv   <<<288,  256, 0, stream>>>(x, wc, bc, Gbt, xtile);
    k2_stats  <<<1152, 512, 0, stream>>>(Gbt, m_part, l_part);
    k2b_merge <<<36,   256, 0, stream>>>(m_part, l_part, mg, rlg);
    kzero     <<<2304, 256, 0, stream>>>(Z);
    k3_pv     <<<576,  512, 0, stream>>>(xtile, Gbt, mg, rlg, Z);
    k4_softmax<<<256,  512, 0, stream>>>(x, Z);
}